// Round 7
// baseline (416.999 us; speedup 1.0000x reference)
//
#include <hip/hip_runtime.h>
#include <hip/hip_bf16.h>

#define NN 50000
#define NE 800000
#define IND 128
#define C 64     // FEAT = HID = OUT

typedef __hip_bfloat16 bf16;
typedef unsigned long long u64;

__device__ __forceinline__ float to_f(float v) { return v; }
__device__ __forceinline__ float to_f(bf16 v)  { return __bfloat162float(v); }

__device__ __forceinline__ unsigned short f2b(float v) {
    unsigned u = __float_as_uint(v);
    return (unsigned short)((u + 0x7FFFu + ((u >> 16) & 1u)) >> 16);   // RNE
}
__device__ __forceinline__ float b2f(unsigned short u) {
    return __uint_as_float((unsigned)u << 16);
}

// --- dtype detect: float inputs fp32 (flag=1) or bf16 (flag=0)? ------------
__global__ void detect_kernel(const unsigned* __restrict__ xu, int* __restrict__ flag) {
    int lane = threadIdx.x;
    unsigned u  = xu[lane];
    unsigned ex = (u >> 7) & 0xFF;
    int vote = (ex >= 90 && ex <= 144) ? 1 : 0;
#pragma unroll
    for (int off = 32; off; off >>= 1) vote += __shfl_xor(vote, off, 64);
    if (lane == 0) *flag = (vote < 40) ? 1 : 0;
}

// --- degree histogram ------------------------------------------------------
__global__ void count_kernel(const int* __restrict__ tgt, int* __restrict__ cnt) {
    int e = blockIdx.x * blockDim.x + threadIdx.x;
    if (e < NE) atomicAdd(&cnt[tgt[e]], 1);
}

// --- single-block exclusive scan (4 counts/thread) -> off; inv = 1/max(c,1)
__global__ __launch_bounds__(1024) void scan_kernel(const int4* __restrict__ cnt4,
                                                    int* __restrict__ off,
                                                    float* __restrict__ inv) {
    __shared__ int wsum[16];
    __shared__ int carry_s;
    int tid = threadIdx.x, lane = tid & 63, wv = tid >> 6;
    if (tid == 0) carry_s = 0;
    __syncthreads();
    const int NV = NN / 4;   // 12500
    for (int base = 0; base < NV; base += 1024) {
        int i = base + tid;
        int4 v = (i < NV) ? cnt4[i] : make_int4(0, 0, 0, 0);
        int tot = v.x + v.y + v.z + v.w;
        int incl = tot;
#pragma unroll
        for (int d = 1; d < 64; d <<= 1) { int t = __shfl_up(incl, d, 64); if (lane >= d) incl += t; }
        if (lane == 63) wsum[wv] = incl;
        __syncthreads();
        if (wv == 0) {
            int ws = (lane < 16) ? wsum[lane] : 0;
#pragma unroll
            for (int d = 1; d < 16; d <<= 1) { int t = __shfl_up(ws, d, 64); if (lane >= d) ws += t; }
            if (lane < 16) wsum[lane] = ws;
        }
        __syncthreads();
        int wbase = (wv == 0) ? 0 : wsum[wv - 1];
        int excl = carry_s + wbase + incl - tot;
        if (i < NV) {
            off[4 * i]     = excl;
            off[4 * i + 1] = excl + v.x;
            off[4 * i + 2] = excl + v.x + v.y;
            off[4 * i + 3] = excl + v.x + v.y + v.z;
            inv[4 * i]     = 1.0f / fmaxf((float)v.x, 1.0f);
            inv[4 * i + 1] = 1.0f / fmaxf((float)v.y, 1.0f);
            inv[4 * i + 2] = 1.0f / fmaxf((float)v.z, 1.0f);
            inv[4 * i + 3] = 1.0f / fmaxf((float)v.w, 1.0f);
        }
        __syncthreads();
        if (tid == 1023) carry_s += wsum[15];
        __syncthreads();
    }
    if (tid == 0) off[NN] = NE;
}

// --- place edges sorted by target: 8B record {u16 src, 3x u16 bf16-ea} -----
// fill[] is pre-initialized to OFF[], so atomicAdd returns the position.
template <typename T>
__device__ __forceinline__ void fill_impl(const int* __restrict__ src, const int* __restrict__ tgt,
                                          const T* __restrict__ ea,
                                          int* __restrict__ fill, u64* __restrict__ edge) {
    int e = blockIdx.x * blockDim.x + threadIdx.x;
    if (e >= NE) return;
    int t = tgt[e];
    int p = atomicAdd(&fill[t], 1);
    unsigned e0, e1, e2;
    if constexpr (sizeof(T) == 2) {
        const unsigned short* eu = (const unsigned short*)ea;
        e0 = eu[e * 3 + 0]; e1 = eu[e * 3 + 1]; e2 = eu[e * 3 + 2];
    } else {
        e0 = f2b(((const float*)ea)[e * 3 + 0]);
        e1 = f2b(((const float*)ea)[e * 3 + 1]);
        e2 = f2b(((const float*)ea)[e * 3 + 2]);
    }
    u64 rec = (u64)((unsigned)src[e] | (e0 << 16)) | ((u64)(e1 | (e2 << 16)) << 32);
    __builtin_nontemporal_store(rec, edge + p);
}

__global__ void fill_kernel(const int* __restrict__ src, const int* __restrict__ tgt,
                            const void* ea, const int* __restrict__ flagp,
                            int* __restrict__ fill, u64* __restrict__ edge) {
    if (*flagp) fill_impl<float>(src, tgt, (const float*)ea, fill, edge);
    else        fill_impl<bf16>(src, tgt, (const bf16*)ea, fill, edge);
}

// --- linear_pre: 64 rows/block, 4x4 register tile; H stored bf16 -----------
template <typename T>
__device__ __forceinline__ void pre_impl(float (*Xl)[132], const T* __restrict__ x,
                                         const T* __restrict__ w, const T* __restrict__ b,
                                         unsigned short* __restrict__ h) {
    int tid = threadIdx.x;
    int nb  = blockIdx.x * 64;
    if constexpr (sizeof(T) == 2) {
        const ushort4* xg = (const ushort4*)(x + (size_t)nb * IND);
        for (int j = tid; j < 64 * 32; j += 256) {
            int row = j >> 5, kk = (j & 31) * 4;
            ushort4 u = (nb + row < NN) ? xg[j] : make_ushort4(0, 0, 0, 0);
            Xl[row][kk]     = b2f(u.x);
            Xl[row][kk + 1] = b2f(u.y);
            Xl[row][kk + 2] = b2f(u.z);
            Xl[row][kk + 3] = b2f(u.w);
        }
    } else {
        const float4* xg = (const float4*)(x + (size_t)nb * IND);
        for (int j = tid; j < 64 * 32; j += 256) {
            int row = j >> 5, kk = (j & 31) * 4;
            float4 v = (nb + row < NN) ? xg[j] : make_float4(0.f, 0.f, 0.f, 0.f);
            Xl[row][kk] = v.x; Xl[row][kk + 1] = v.y; Xl[row][kk + 2] = v.z; Xl[row][kk + 3] = v.w;
        }
    }
    __syncthreads();
    int tx = tid & 15, ty = tid >> 4, c0 = tx * 4;
    float acc[4][4];
#pragma unroll
    for (int r = 0; r < 4; ++r)
#pragma unroll
        for (int j = 0; j < 4; ++j) acc[r][j] = to_f(b[c0 + j]);
    for (int k = 0; k < IND; k += 4) {
#pragma unroll
        for (int kk = 0; kk < 4; ++kk) {
            float wv[4];
#pragma unroll
            for (int j = 0; j < 4; ++j) wv[j] = to_f(w[(k + kk) * C + c0 + j]);
#pragma unroll
            for (int r = 0; r < 4; ++r) {
                float sv = Xl[ty + 16 * r][k + kk];
#pragma unroll
                for (int j = 0; j < 4; ++j) acc[r][j] += sv * wv[j];
            }
        }
    }
#pragma unroll
    for (int r = 0; r < 4; ++r) {
        int row = nb + ty + 16 * r;
        if (row < NN) {
            ushort4 uv = make_ushort4(f2b(acc[r][0]), f2b(acc[r][1]), f2b(acc[r][2]), f2b(acc[r][3]));
            *(ushort4*)(h + (size_t)row * C + c0) = uv;
        }
    }
}

__global__ __launch_bounds__(256) void pre_kernel(const void* x, const void* w, const void* b,
                                                  const int* __restrict__ flagp,
                                                  unsigned short* __restrict__ h) {
    __shared__ float Xl[64][132];
    if (*flagp) pre_impl<float>(Xl, (const float*)x, (const float*)w, (const float*)b, h);
    else        pre_impl<bf16>(Xl, (const bf16*)x, (const bf16*)w, (const bf16*)b, h);
}

// --- aggregation: one wave/node, software-pipelined, 8B records, bf16 S ----
__global__ __launch_bounds__(256) void agg_kernel(const unsigned short* __restrict__ hb,
                                                  const uint2* __restrict__ edge,
                                                  const int* __restrict__ off,
                                                  const float* __restrict__ inv,
                                                  unsigned short* __restrict__ s) {
    int f = threadIdx.x & 63;
    int n = blockIdx.x * 4 + (threadIdx.x >> 6);
    int beg = __builtin_amdgcn_readfirstlane(off[n]);
    int end = __builtin_amdgcn_readfirstlane(off[n + 1]);
    float a0 = 0.f, a1 = 0.f, a2 = 0.f;
    int e = beg;
    int m4 = beg + ((end - beg) & ~3);
    if (e < m4) {
        uint2 c0 = edge[e], c1 = edge[e + 1], c2 = edge[e + 2], c3 = edge[e + 3];
        e += 4;
        for (; e < m4; e += 4) {
            float h0 = b2f(hb[((c0.x & 0xFFFF) << 6) + f]);
            float h1 = b2f(hb[((c1.x & 0xFFFF) << 6) + f]);
            float h2 = b2f(hb[((c2.x & 0xFFFF) << 6) + f]);
            float h3 = b2f(hb[((c3.x & 0xFFFF) << 6) + f]);
            uint2 n0 = edge[e], n1 = edge[e + 1], n2 = edge[e + 2], n3 = edge[e + 3];
            a0 += b2f((unsigned short)(c0.x >> 16)) * h0;
            a1 += b2f((unsigned short)(c0.y & 0xFFFF)) * h0;
            a2 += b2f((unsigned short)(c0.y >> 16)) * h0;
            a0 += b2f((unsigned short)(c1.x >> 16)) * h1;
            a1 += b2f((unsigned short)(c1.y & 0xFFFF)) * h1;
            a2 += b2f((unsigned short)(c1.y >> 16)) * h1;
            a0 += b2f((unsigned short)(c2.x >> 16)) * h2;
            a1 += b2f((unsigned short)(c2.y & 0xFFFF)) * h2;
            a2 += b2f((unsigned short)(c2.y >> 16)) * h2;
            a0 += b2f((unsigned short)(c3.x >> 16)) * h3;
            a1 += b2f((unsigned short)(c3.y & 0xFFFF)) * h3;
            a2 += b2f((unsigned short)(c3.y >> 16)) * h3;
            c0 = n0; c1 = n1; c2 = n2; c3 = n3;
        }
        float h0 = b2f(hb[((c0.x & 0xFFFF) << 6) + f]);
        float h1 = b2f(hb[((c1.x & 0xFFFF) << 6) + f]);
        float h2 = b2f(hb[((c2.x & 0xFFFF) << 6) + f]);
        float h3 = b2f(hb[((c3.x & 0xFFFF) << 6) + f]);
        a0 += b2f((unsigned short)(c0.x >> 16)) * h0;
        a1 += b2f((unsigned short)(c0.y & 0xFFFF)) * h0;
        a2 += b2f((unsigned short)(c0.y >> 16)) * h0;
        a0 += b2f((unsigned short)(c1.x >> 16)) * h1;
        a1 += b2f((unsigned short)(c1.y & 0xFFFF)) * h1;
        a2 += b2f((unsigned short)(c1.y >> 16)) * h1;
        a0 += b2f((unsigned short)(c2.x >> 16)) * h2;
        a1 += b2f((unsigned short)(c2.y & 0xFFFF)) * h2;
        a2 += b2f((unsigned short)(c2.y >> 16)) * h2;
        a0 += b2f((unsigned short)(c3.x >> 16)) * h3;
        a1 += b2f((unsigned short)(c3.y & 0xFFFF)) * h3;
        a2 += b2f((unsigned short)(c3.y >> 16)) * h3;
    }
    for (; e < end; ++e) {
        uint2 r = edge[e];
        float hv = b2f(hb[((r.x & 0xFFFF) << 6) + f]);
        a0 += b2f((unsigned short)(r.x >> 16)) * hv;
        a1 += b2f((unsigned short)(r.y & 0xFFFF)) * hv;
        a2 += b2f((unsigned short)(r.y >> 16)) * hv;
    }
    float iv = inv[n];
    unsigned short* so = s + (size_t)n * 192;
    so[f]       = f2b(a0 * iv);
    so[64 + f]  = f2b(a1 * iv);
    so[128 + f] = f2b(a2 * iv);
}

// --- dense: out = S @ W + b; MODE 0: relu -> H(bf16); MODE 1: L2-norm ------
template <typename T, int MODE>
__device__ __forceinline__ void gemm_impl(float (*Sl)[196], const unsigned short* __restrict__ sb,
                                          const T* __restrict__ w, const T* __restrict__ b,
                                          unsigned short* __restrict__ hout, T* __restrict__ out) {
    int tid = threadIdx.x;
    int nb  = blockIdx.x * 64;
    const ushort4* sg = (const ushort4*)(sb + (size_t)nb * 192);
    for (int j = tid; j < 64 * 48; j += 256) {               // 48 ushort4 per row
        int row = j / 48, kk = (j % 48) * 4;
        ushort4 u = (nb + row < NN) ? sg[j] : make_ushort4(0, 0, 0, 0);
        Sl[row][kk]     = b2f(u.x);
        Sl[row][kk + 1] = b2f(u.y);
        Sl[row][kk + 2] = b2f(u.z);
        Sl[row][kk + 3] = b2f(u.w);
    }
    __syncthreads();
    int tx = tid & 15, ty = tid >> 4, c0 = tx * 4;
    float acc[4][4];
#pragma unroll
    for (int r = 0; r < 4; ++r)
#pragma unroll
        for (int j = 0; j < 4; ++j) acc[r][j] = to_f(b[c0 + j]);
    for (int k = 0; k < 192; k += 4) {
#pragma unroll
        for (int kk = 0; kk < 4; ++kk) {
            float wv[4];
#pragma unroll
            for (int j = 0; j < 4; ++j) wv[j] = to_f(w[(k + kk) * C + c0 + j]);
#pragma unroll
            for (int r = 0; r < 4; ++r) {
                float sv = Sl[ty + 16 * r][k + kk];
#pragma unroll
                for (int j = 0; j < 4; ++j) acc[r][j] += sv * wv[j];
            }
        }
    }
#pragma unroll
    for (int r = 0; r < 4; ++r) {
        int row = nb + ty + 16 * r;
        if constexpr (MODE == 0) {
            if (row < NN) {
                ushort4 uv = make_ushort4(f2b(fmaxf(acc[r][0], 0.f)), f2b(fmaxf(acc[r][1], 0.f)),
                                          f2b(fmaxf(acc[r][2], 0.f)), f2b(fmaxf(acc[r][3], 0.f)));
                *(ushort4*)(hout + (size_t)row * C + c0) = uv;
            }
        } else {
            float sq = acc[r][0] * acc[r][0] + acc[r][1] * acc[r][1]
                     + acc[r][2] * acc[r][2] + acc[r][3] * acc[r][3];
#pragma unroll
            for (int o = 1; o < 16; o <<= 1) sq += __shfl_xor(sq, o, 64);
            float innorm = 1.0f / fmaxf(sqrtf(sq), 1e-12f);
            if (row < NN) {
#pragma unroll
                for (int j = 0; j < 4; ++j) {
                    float rv = acc[r][j] * innorm;
                    if constexpr (sizeof(T) == 2) out[(size_t)row * C + c0 + j] = __float2bfloat16(rv);
                    else                          out[(size_t)row * C + c0 + j] = rv;
                }
            }
        }
    }
}

__global__ __launch_bounds__(256) void gemm_relu(const unsigned short* __restrict__ sb, const void* w,
                                                 const void* b, const int* __restrict__ flagp,
                                                 unsigned short* __restrict__ hout) {
    __shared__ float Sl[64][196];
    if (*flagp) gemm_impl<float, 0>(Sl, sb, (const float*)w, (const float*)b, hout, (float*)nullptr);
    else        gemm_impl<bf16, 0>(Sl, sb, (const bf16*)w, (const bf16*)b, hout, (bf16*)nullptr);
}

__global__ __launch_bounds__(256) void gemm_norm(const unsigned short* __restrict__ sb, const void* w,
                                                 const void* b, const int* __restrict__ flagp,
                                                 void* out) {
    __shared__ float Sl[64][196];
    if (*flagp) gemm_impl<float, 1>(Sl, sb, (const float*)w, (const float*)b, nullptr, (float*)out);
    else        gemm_impl<bf16, 1>(Sl, sb, (const bf16*)w, (const bf16*)b, nullptr, (bf16*)out);
}

extern "C" void kernel_launch(void* const* d_in, const int* in_sizes, int n_in,
                              void* d_out, int out_size, void* d_ws, size_t ws_size,
                              hipStream_t stream) {
    const void* x     = d_in[0];
    const int*  ei    = (const int*)d_in[1];
    const void* ea    = d_in[2];
    const void* pre_w = d_in[3];
    const void* pre_b = d_in[4];
    const void* W[3]  = {d_in[5], d_in[7], d_in[9]};
    const void* B[3]  = {d_in[6], d_in[8], d_in[10]};
    const int* src = ei;
    const int* tgt = ei + NE;

    // ws layout: EDGE u64[NE] | S bf16[NN*192] | H bf16[NN*64] | CNT[NN]
    //            | OFF[NN+4] | FILL[NN] | INV[NN] | FLAG    (~33 MB total)
    u64*            EDGE = (u64*)d_ws;                            // 6.4 MB
    unsigned short* S    = (unsigned short*)(EDGE + NE);          // 19.2 MB
    unsigned short* H    = S + (size_t)NN * 192;                  // 6.4 MB
    int*            CNT  = (int*)(H + (size_t)NN * C);
    int*            OFF  = CNT + NN;
    int*            FILL = OFF + NN + 4;
    float*          INV  = (float*)(FILL + NN);
    int*            FLAG = (int*)(INV + NN);

    detect_kernel<<<1, 64, 0, stream>>>((const unsigned*)x, FLAG);
    hipMemsetAsync(CNT, 0, NN * sizeof(int), stream);
    count_kernel<<<(NE + 255) / 256, 256, 0, stream>>>(tgt, CNT);
    scan_kernel<<<1, 1024, 0, stream>>>((const int4*)CNT, OFF, INV);
    hipMemcpyAsync(FILL, OFF, NN * sizeof(int), hipMemcpyDeviceToDevice, stream);
    fill_kernel<<<(NE + 255) / 256, 256, 0, stream>>>(src, tgt, ea, FLAG, FILL, EDGE);
    pre_kernel<<<(NN + 63) / 64, 256, 0, stream>>>(x, pre_w, pre_b, FLAG, H);

    for (int l = 0; l < 3; ++l) {
        agg_kernel<<<NN / 4, 256, 0, stream>>>(H, (const uint2*)EDGE, OFF, INV, S);
        if (l < 2)
            gemm_relu<<<(NN + 63) / 64, 256, 0, stream>>>(S, W[l], B[l], FLAG, H);
        else
            gemm_norm<<<(NN + 63) / 64, 256, 0, stream>>>(S, W[l], B[l], FLAG, d_out);
    }
}